// Round 1
// baseline (462.949 us; speedup 1.0000x reference)
//
#include <hip/hip_runtime.h>
#include <stdint.h>

typedef __attribute__((ext_vector_type(8))) short short8;
typedef __attribute__((ext_vector_type(4))) float f32x4;
typedef __attribute__((ext_vector_type(4))) uint32_t u32x4;
typedef __attribute__((ext_vector_type(2))) uint32_t u32x2;
typedef __attribute__((ext_vector_type(4))) unsigned short u16x4;

#define K_TOP 410

// ws layout (byte offsets)
#define WS_ABSMAX 0
#define WS_GSUM   1024
#define WS_GSQ    3072
#define WS_SCALE  5120
#define WS_SHIFT  7168
#define WS_SUB    16384      // 8192 f32
#define WS_MASK   65536      // 16384 f32
#define WS_BMAT   131072     // 2M ushort (4 MB), layout [cout][cin*16+kh*4+kw] == weight layout

__device__ __forceinline__ unsigned short f2bf(float f) {
  uint32_t u = __float_as_uint(f);
  u += 0x7fffu + ((u >> 16) & 1u);   // RTNE
  return (unsigned short)(u >> 16);
}

// ---------------- stage 1: sub[b][cin] = mean |x| over 64x64 ----------------
__global__ void k_sub(const float* __restrict__ x, float* __restrict__ sub) {
  int bid = blockIdx.x;                       // 0..8191 = b*256+cin
  const f32x4* xp = (const f32x4*)(x + (size_t)bid * 4096);
  int t = threadIdx.x;
  float s = 0.f;
#pragma unroll
  for (int i = 0; i < 4; ++i) {
    f32x4 v = xp[t + i * 256];
    s += fabsf(v.x) + fabsf(v.y) + fabsf(v.z) + fabsf(v.w);
  }
#pragma unroll
  for (int off = 32; off > 0; off >>= 1) s += __shfl_xor(s, off);
  __shared__ float red[4];
  if ((t & 63) == 0) red[t >> 6] = s;
  __syncthreads();
  if (t == 0) sub[bid] = (red[0] + red[1] + red[2] + red[3]) * (1.f / 4096.f);
}

// ---------------- stage 2: max|W| ----------------
__global__ void k_wmax(const float* __restrict__ w, unsigned int* __restrict__ wsmax) {
  int t = blockIdx.x * 256 + threadIdx.x;
  const f32x4* wp = (const f32x4*)w;
  float m = 0.f;
#pragma unroll
  for (int i = 0; i < 8; ++i) {
    f32x4 v = wp[t + i * 65536];
    m = fmaxf(m, fmaxf(fmaxf(fabsf(v.x), fabsf(v.y)), fmaxf(fabsf(v.z), fabsf(v.w))));
  }
#pragma unroll
  for (int off = 32; off > 0; off >>= 1) m = fmaxf(m, __shfl_xor(m, off));
  __shared__ float red[4];
  if ((threadIdx.x & 63) == 0) red[threadIdx.x >> 6] = m;
  __syncthreads();
  if (threadIdx.x == 0) {
    m = fmaxf(fmaxf(red[0], red[1]), fmaxf(red[2], red[3]));
    atomicMax(wsmax, __float_as_uint(m));   // all values >= 0: uint order == float order
  }
}

// ---------------- stage 3: saliency + top-k threshold -> mask[b][cout] ----------------
__global__ void k_mask(const float* __restrict__ sub, const float* __restrict__ salw,
                       const float* __restrict__ salb, float* __restrict__ mask) {
  int b = blockIdx.x, n = threadIdx.x;  // 512 threads
  __shared__ float subs[256];
  __shared__ float sals[512];
  __shared__ float thr_s;
  if (n < 256) subs[n] = sub[b * 256 + n];
  __syncthreads();
  float acc = salb[n];
#pragma unroll 4
  for (int c = 0; c < 256; ++c) acc += subs[c] * salw[n * 256 + c];
  float sal = fabsf(acc);
  sals[n] = sal;
  __syncthreads();
  int gt = 0, eq = 0;
  for (int j = 0; j < 512; ++j) {
    float v = sals[j];
    gt += (v > sal);
    eq += (v == sal);
  }
  if (gt < K_TOP && gt + eq >= K_TOP) thr_s = sal;  // unique value; benign multi-write
  __syncthreads();
  mask[b * 512 + n] = (sal > thr_s) ? sal : 0.f;
}

// ---------------- stage 4: ternarize weight -> bf16 Bmat (same layout as weight) ----------------
__global__ void k_quant(const float* __restrict__ w, const unsigned int* __restrict__ wsmax,
                        const float* __restrict__ posp, const float* __restrict__ negp,
                        unsigned short* __restrict__ bmat) {
  int t = blockIdx.x * 256 + threadIdx.x;        // 0..524287 (x4 elems)
  float thr = 0.05f * __uint_as_float(*wsmax);
  unsigned short bp = f2bf(*posp), bn = f2bf(*negp);
  f32x4 v = ((const f32x4*)w)[t];
  u16x4 q;
  q.x = v.x > thr ? bp : (v.x < -thr ? bn : (unsigned short)0);
  q.y = v.y > thr ? bp : (v.y < -thr ? bn : (unsigned short)0);
  q.z = v.z > thr ? bp : (v.z < -thr ? bn : (unsigned short)0);
  q.w = v.w > thr ? bp : (v.w < -thr ? bn : (unsigned short)0);
  ((u16x4*)bmat)[t] = q;
}

// ---------------- stage 5: implicit-GEMM conv + mask + per-channel partial sums ----------------
// M=32768 (b,oh,ow), N=512 (cout), K=4096 (cin,kh,kw). BM=128,BN=128,BK=32 (2 cins/step).
__launch_bounds__(256, 2)
__global__ void k_gemm(const float* __restrict__ x, const unsigned short* __restrict__ bmat,
                       const float* __restrict__ mask, float* __restrict__ out,
                       float* __restrict__ gsum, float* __restrict__ gsq) {
  // x tile: 2 cins x 10 rows x 68 cols (col = iw+1; cols 0,65 are zero pad; 66..67 unused pad)
  __shared__ __align__(16) unsigned short xs[2 * 10 * 68];   // 2720 B
  __shared__ __align__(16) unsigned short bs[128 * 32];      // 8192 B

  int tid = threadIdx.x;
  int lane = tid & 63, wid = tid >> 6;
  int wm = wid >> 1, wn = wid & 1;
  int g = lane >> 4, lr = lane & 15;

  // bijective XCD swizzle: 1024 wgs, 8 XCDs -> chunks of 128
  int orig = blockIdx.x;
  int wg = (orig & 7) * 128 + (orig >> 3);
  int nt = wg & 3, mt = wg >> 2;       // nt: N-tile 0..3, mt: M-tile 0..255
  int b = mt >> 3, oh0 = (mt & 7) * 4;
  int n0 = nt * 128;

  f32x4 acc[4][4];
#pragma unroll
  for (int i = 0; i < 4; ++i)
#pragma unroll
    for (int j = 0; j < 4; ++j) acc[i][j] = (f32x4){0.f, 0.f, 0.f, 0.f};

  // x staging precompute (fid: row=fid>>4 in [0,20), j=fid&15)
  // row -> c2=row/10, R=row%10, ih = 2*oh0-1+R
  const size_t xb = (size_t)b * 256 * 4096;

  for (int kt = 0; kt < 128; ++kt) {
    int cin0 = kt * 2;
    // ---- stage x rows into LDS (bf16, col shifted +1 via shfl_up) ----
#pragma unroll
    for (int batch = 0; batch < 2; ++batch) {
      int fid = tid + batch * 256;
      if (batch == 0 || tid < 64) {
        int row = fid >> 4, j = fid & 15;
        int c2 = (row >= 10) ? 1 : 0;
        int R = row - c2 * 10;
        int ih = 2 * oh0 - 1 + R;
        bool valid = ((unsigned)ih < 64u);
        f32x4 v = (f32x4){0.f, 0.f, 0.f, 0.f};
        if (valid)
          v = *(const f32x4*)(x + xb + ((size_t)(cin0 + c2) * 64 + ih) * 64 + 4 * j);
        float pw = __shfl_up(v.w, 1);
        if (j == 0) pw = 0.f;                       // left zero-pad (iw = -1)
        uint32_t lo = (uint32_t)f2bf(pw) | ((uint32_t)f2bf(v.x) << 16);
        uint32_t hi = (uint32_t)f2bf(v.y) | ((uint32_t)f2bf(v.z) << 16);
        *(u32x2*)&xs[row * 68 + 4 * j] = (u32x2){lo, hi};
        if (j == 15)                                 // cols 64,65 = {x[63], 0}
          *(uint32_t*)&xs[row * 68 + 64] = (uint32_t)f2bf(v.w);
      }
    }
    // ---- stage B tile with bank XOR-swizzle (seg ^= (n>>1)&3) ----
#pragma unroll
    for (int q = 0; q < 2; ++q) {
      int slot = tid + q * 256;          // 0..511
      int n = slot >> 2, sl = slot & 3;
      int sg = sl ^ ((n >> 1) & 3);
      u32x4 v = *(const u32x4*)(bmat + (size_t)(n0 + n) * 4096 + kt * 32 + sg * 8);
      *(u32x4*)&bs[n * 32 + sl * 8] = v;
    }
    __syncthreads();
    // ---- compute ----
    short8 bf[4];
#pragma unroll
    for (int ni = 0; ni < 4; ++ni) {
      int n = wn * 64 + ni * 16 + lr;
      int sl = g ^ ((n >> 1) & 3);
      bf[ni] = *(const short8*)&bs[n * 32 + sl * 8];
    }
    const uint32_t* x32 = (const uint32_t*)xs;
#pragma unroll
    for (int mi = 0; mi < 4; ++mi) {
      int mloc = wm * 64 + mi * 16 + lr;
      int ow = mloc & 31;
      int R0 = 2 * (mloc >> 5) + 2 * (g & 1);
      int c2 = g >> 1;
      int di = (c2 * 10 + R0) * 34 + ow;           // dword index (row stride 68 elems = 34 dwords)
      uint32_t d0 = x32[di], d1 = x32[di + 1], d2 = x32[di + 34], d3 = x32[di + 35];
      union { uint32_t u[4]; short8 s; } af;
      af.u[0] = d0; af.u[1] = d1; af.u[2] = d2; af.u[3] = d3;
#pragma unroll
      for (int ni = 0; ni < 4; ++ni)
        acc[mi][ni] = __builtin_amdgcn_mfma_f32_16x16x32_bf16(af.s, bf[ni], acc[mi][ni], 0, 0, 0);
    }
    __syncthreads();
  }

  // ---- epilogue: mask, store, per-channel sums ----
  float msk[4];
#pragma unroll
  for (int ni = 0; ni < 4; ++ni) msk[ni] = mask[b * 512 + n0 + wn * 64 + ni * 16 + lr];

  float psum[4] = {0.f, 0.f, 0.f, 0.f}, psq[4] = {0.f, 0.f, 0.f, 0.f};
#pragma unroll
  for (int ni = 0; ni < 4; ++ni) {
    int n = n0 + wn * 64 + ni * 16 + lr;
    float* op = out + (size_t)b * 524288 + (size_t)n * 1024 + (mt & 7) * 128 + wm * 64 + 4 * g;
#pragma unroll
    for (int mi = 0; mi < 4; ++mi) {
      f32x4 a = acc[mi][ni] * msk[ni];
      psum[ni] += a.x + a.y + a.z + a.w;
      psq[ni] += a.x * a.x + a.y * a.y + a.z * a.z + a.w * a.w;
      *(f32x4*)(op + mi * 16) = a;
    }
  }
#pragma unroll
  for (int ni = 0; ni < 4; ++ni) {
    float s = psum[ni], q = psq[ni];
    s += __shfl_xor(s, 16); s += __shfl_xor(s, 32);
    q += __shfl_xor(q, 16); q += __shfl_xor(q, 32);
    if (g == 0) {
      int n = n0 + wn * 64 + ni * 16 + lr;
      atomicAdd(&gsum[n], s);
      atomicAdd(&gsq[n], q);
    }
  }
}

// ---------------- stage 6: BN params ----------------
__global__ void k_bnprep(const float* __restrict__ gsum, const float* __restrict__ gsq,
                         const float* __restrict__ gamma, const float* __restrict__ beta,
                         float* __restrict__ scale, float* __restrict__ shift) {
  int n = threadIdx.x;
  float mu = gsum[n] * (1.f / 32768.f);
  float var = gsq[n] * (1.f / 32768.f) - mu * mu;
  float a = gamma[n] * rsqrtf(var + 1e-5f);
  scale[n] = a;
  shift[n] = beta[n] - mu * a;
}

// ---------------- stage 7: BN apply + LeakyReLU (in place) ----------------
__global__ void k_bn(float* __restrict__ y, const float* __restrict__ scale,
                     const float* __restrict__ shift) {
  int t = blockIdx.x * 256 + threadIdx.x;   // 524288 threads
  f32x4* yp = (f32x4*)y;
#pragma unroll
  for (int i = 0; i < 8; ++i) {
    int idx = t + i * 524288;
    int n = (idx >> 8) & 511;               // 256 float4 per (b,n) plane row-block
    f32x4 v = yp[idx];
    float a = scale[n], sh = shift[n];
    v = v * a + sh;
    v.x = v.x > 0.f ? v.x : 0.2f * v.x;
    v.y = v.y > 0.f ? v.y : 0.2f * v.y;
    v.z = v.z > 0.f ? v.z : 0.2f * v.z;
    v.w = v.w > 0.f ? v.w : 0.2f * v.w;
    yp[idx] = v;
  }
}

extern "C" void kernel_launch(void* const* d_in, const int* in_sizes, int n_in,
                              void* d_out, int out_size, void* d_ws, size_t ws_size,
                              hipStream_t stream) {
  const float* x     = (const float*)d_in[0];
  const float* w     = (const float*)d_in[1];
  const float* pos   = (const float*)d_in[2];
  const float* neg   = (const float*)d_in[3];
  const float* salw  = (const float*)d_in[4];
  const float* salb  = (const float*)d_in[5];
  const float* gamma = (const float*)d_in[6];
  const float* beta  = (const float*)d_in[7];
  float* out = (float*)d_out;
  char* ws = (char*)d_ws;

  unsigned int* absmax = (unsigned int*)(ws + WS_ABSMAX);
  float* gsum  = (float*)(ws + WS_GSUM);
  float* gsq   = (float*)(ws + WS_GSQ);
  float* scale = (float*)(ws + WS_SCALE);
  float* shift = (float*)(ws + WS_SHIFT);
  float* sub   = (float*)(ws + WS_SUB);
  float* mask  = (float*)(ws + WS_MASK);
  unsigned short* bmat = (unsigned short*)(ws + WS_BMAT);

  hipMemsetAsync(ws, 0, 5120, stream);   // absmax + gsum + gsq

  k_sub<<<8192, 256, 0, stream>>>(x, sub);
  k_wmax<<<256, 256, 0, stream>>>(w, absmax);
  k_mask<<<32, 512, 0, stream>>>(sub, salw, salb, mask);
  k_quant<<<2048, 256, 0, stream>>>(w, absmax, pos, neg, bmat);
  k_gemm<<<1024, 256, 0, stream>>>(x, bmat, mask, out, gsum, gsq);
  k_bnprep<<<1, 512, 0, stream>>>(gsum, gsq, gamma, beta, scale, shift);
  k_bn<<<2048, 256, 0, stream>>>(out, scale, shift);
}

// Round 2
// 462.642 us; speedup vs baseline: 1.0007x; 1.0007x over previous
//
#include <hip/hip_runtime.h>
#include <stdint.h>

typedef __attribute__((ext_vector_type(8))) short short8;
typedef __attribute__((ext_vector_type(4))) float f32x4;
typedef __attribute__((ext_vector_type(4))) uint32_t u32x4;
typedef __attribute__((ext_vector_type(4))) unsigned short u16x4;

#define K_TOP 410

// ws layout (byte offsets)
#define WS_ABSMAX 0
#define WS_GSUM   1024
#define WS_GSQ    3072
#define WS_SCALE  5120
#define WS_SHIFT  7168
#define WS_SUB    16384      // 8192 f32
#define WS_MASK   65536      // 16384 f32
#define WS_BMAT   131072     // 4 MB: pre-tiled swizzled bf16 weights
// bmat2 layout: [nt 0..1][kt 0..63][chunk c 0..2047] x 16B, c=(n<<3)|sp,
// content = W[nt*256+n][k64 = 8*s .. 8*s+7] with s = sp ^ (n&7), k64 = cin_l*16+kh*4+kw

__device__ __forceinline__ unsigned short f2bf(float f) {
  uint32_t u = __float_as_uint(f);
  u += 0x7fffu + ((u >> 16) & 1u);   // RTNE
  return (unsigned short)(u >> 16);
}

__device__ __forceinline__ uint32_t pkbf(float a, float b) {
  uint32_t r;
  asm("v_cvt_pk_bf16_f32 %0, %1, %2" : "=v"(r) : "v"(a), "v"(b));
  return r;
}

// ---------------- stage 1: sub[b][cin] = mean |x| over 64x64 ----------------
__global__ void k_sub(const float* __restrict__ x, float* __restrict__ sub) {
  int bid = blockIdx.x;                       // b*256+cin
  const f32x4* xp = (const f32x4*)(x + (size_t)bid * 4096);
  int t = threadIdx.x;
  float s = 0.f;
#pragma unroll
  for (int i = 0; i < 4; ++i) {
    f32x4 v = xp[t + i * 256];
    s += fabsf(v.x) + fabsf(v.y) + fabsf(v.z) + fabsf(v.w);
  }
#pragma unroll
  for (int off = 32; off > 0; off >>= 1) s += __shfl_xor(s, off);
  __shared__ float red[4];
  if ((t & 63) == 0) red[t >> 6] = s;
  __syncthreads();
  if (t == 0) sub[bid] = (red[0] + red[1] + red[2] + red[3]) * (1.f / 4096.f);
}

// ---------------- stage 2: max|W| ----------------
__global__ void k_wmax(const float* __restrict__ w, unsigned int* __restrict__ wsmax) {
  int t = blockIdx.x * 256 + threadIdx.x;
  const f32x4* wp = (const f32x4*)w;
  float m = 0.f;
#pragma unroll
  for (int i = 0; i < 8; ++i) {
    f32x4 v = wp[t + i * 65536];
    m = fmaxf(m, fmaxf(fmaxf(fabsf(v.x), fabsf(v.y)), fmaxf(fabsf(v.z), fabsf(v.w))));
  }
#pragma unroll
  for (int off = 32; off > 0; off >>= 1) m = fmaxf(m, __shfl_xor(m, off));
  __shared__ float red[4];
  if ((threadIdx.x & 63) == 0) red[threadIdx.x >> 6] = m;
  __syncthreads();
  if (threadIdx.x == 0) {
    m = fmaxf(fmaxf(red[0], red[1]), fmaxf(red[2], red[3]));
    atomicMax(wsmax, __float_as_uint(m));
  }
}

// ---------------- stage 3: saliency + top-k threshold -> mask[b][cout] ----------------
__global__ void k_mask(const float* __restrict__ sub, const float* __restrict__ salw,
                       const float* __restrict__ salb, float* __restrict__ mask) {
  int b = blockIdx.x, n = threadIdx.x;  // 512 threads
  __shared__ float subs[256];
  __shared__ float sals[512];
  __shared__ float thr_s;
  if (n < 256) subs[n] = sub[b * 256 + n];
  __syncthreads();
  float acc = salb[n];
#pragma unroll 4
  for (int c = 0; c < 256; ++c) acc += subs[c] * salw[n * 256 + c];
  float sal = fabsf(acc);
  sals[n] = sal;
  __syncthreads();
  int gt = 0, eq = 0;
  for (int j = 0; j < 512; ++j) {
    float v = sals[j];
    gt += (v > sal);
    eq += (v == sal);
  }
  if (gt < K_TOP && gt + eq >= K_TOP) thr_s = sal;
  __syncthreads();
  mask[b * 512 + n] = (sal > thr_s) ? sal : 0.f;
}

// ---------------- stage 4: ternarize weight -> pre-tiled swizzled bf16 bmat2 ----------------
__global__ void k_quant(const float* __restrict__ w, const unsigned int* __restrict__ wsmax,
                        const float* __restrict__ posp, const float* __restrict__ negp,
                        unsigned short* __restrict__ bmat2) {
  int id = blockIdx.x * 256 + threadIdx.x;        // chunk id 0..262143
  int c = id & 2047;
  int ktq = (id >> 11) & 63;
  int ntq = id >> 17;
  int n = c >> 3, sp = c & 7;
  int s = sp ^ (n & 7);
  int cout = ntq * 256 + n;
  const float* src = w + (size_t)cout * 4096 + ktq * 64 + s * 8;
  float thr = 0.05f * __uint_as_float(*wsmax);
  unsigned short bp = f2bf(*posp), bn = f2bf(*negp);
  f32x4 a = *(const f32x4*)src;
  f32x4 bq = *(const f32x4*)(src + 4);
  u16x4 q0, q1;
  q0.x = a.x > thr ? bp : (a.x < -thr ? bn : (unsigned short)0);
  q0.y = a.y > thr ? bp : (a.y < -thr ? bn : (unsigned short)0);
  q0.z = a.z > thr ? bp : (a.z < -thr ? bn : (unsigned short)0);
  q0.w = a.w > thr ? bp : (a.w < -thr ? bn : (unsigned short)0);
  q1.x = bq.x > thr ? bp : (bq.x < -thr ? bn : (unsigned short)0);
  q1.y = bq.y > thr ? bp : (bq.y < -thr ? bn : (unsigned short)0);
  q1.z = bq.z > thr ? bp : (bq.z < -thr ? bn : (unsigned short)0);
  q1.w = bq.w > thr ? bp : (bq.w < -thr ? bn : (unsigned short)0);
  ((u16x4*)bmat2)[id * 2]     = q0;
  ((u16x4*)bmat2)[id * 2 + 1] = q1;
}

// ---------------- stage 5: implicit-GEMM conv, 256x256 tile, BK=64, dbuf ----------------
// M=32768, N=512, K=4096. 256 blocks (128 M-tiles x 2 N-tiles), 512 thr = 8 waves (2m x 4n),
// wave tile 128x64. A-LDS: im2col pair-units [rowidx 0..35][unit 0..31] x 16B, evens-then-odds.
__launch_bounds__(512, 2)
__global__ void k_gemm(const float* __restrict__ x, const unsigned short* __restrict__ bmat2,
                       const float* __restrict__ mask, float* __restrict__ out,
                       float* __restrict__ gsum, float* __restrict__ gsq) {
  __shared__ __align__(16) unsigned short xsL[2][36 * 32 * 8];   // 2 x 18 KB
  __shared__ __align__(16) unsigned short bsL[2][2048 * 8];      // 2 x 32 KB

  int tid = threadIdx.x;
  int lane = tid & 63, wid = tid >> 6;
  int wm = wid >> 2, wn = wid & 3;
  int g = lane >> 4, lr = lane & 15;

  int wg = blockIdx.x;
  int nt = wg & 1, mt = wg >> 1;         // mt 0..127
  int b = mt >> 2, OH0 = (mt & 3) * 8;
  const size_t xb = (size_t)b * 256 * 4096;

  // ---- A staging task descriptors ----
  // task0 (all threads): t=tid -> rowidx=tid>>4 (0..31), j=tid&15
  int jA = tid & 15, riA = tid >> 4;
  int c2A = riA / 9, rpA = riA - c2A * 9;
  int ihA = 2 * (OH0 + rpA) - 1;
  bool vA0 = (unsigned)ihA < 64u, vA1 = (unsigned)(ihA + 1) < 64u;
  const float* pA = x + xb + (size_t)c2A * 4096 + (long)ihA * 64 + 4 * jA;
  // task1 (waves 0..3, lanes 0..15): rowidx = 32+wid (c2=3, rp=5+wid), j=lane
  bool hasB = (wid < 4) && (lane < 16);
  int riB = 32 + wid, jB = lane;
  int rpB = riB - 27;
  int ihB = 2 * (OH0 + rpB) - 1;
  bool vB0 = (unsigned)ihB < 64u, vB1 = (unsigned)(ihB + 1) < 64u;
  const float* pB = x + xb + (size_t)3 * 4096 + (long)ihB * 64 + 4 * jB;

  f32x4 acc[8][4];
#pragma unroll
  for (int i = 0; i < 8; ++i)
#pragma unroll
    for (int j = 0; j < 4; ++j) acc[i][j] = (f32x4){0.f, 0.f, 0.f, 0.f};

  auto ldrow = [&](const float* p, bool v, int j, f32x4& vv, float& pw, float& nx) {
    vv = (f32x4){0.f, 0.f, 0.f, 0.f}; pw = 0.f; nx = 0.f;
    if (v) {
      vv = *(const f32x4*)p;
      if (j != 0)  pw = p[-1];
      if (j != 15) nx = p[4];
    }
  };
  auto wtask = [&](int buf, int rowidx, int j, const f32x4& v0, const f32x4& v1,
                   float pw0, float nx0, float pw1, float nx1) {
    uint32_t a0 = pkbf(pw0, v0.x), b0 = pkbf(v0.y, v0.z), c0 = pkbf(v0.w, nx0);
    uint32_t a1 = pkbf(pw1, v1.x), b1 = pkbf(v1.y, v1.z), c1 = pkbf(v1.w, nx1);
    u32x4* dst = (u32x4*)&xsL[buf][0];
    dst[rowidx * 32 + j]      = (u32x4){a0, b0, a1, b1};   // ow = 2j
    dst[rowidx * 32 + 16 + j] = (u32x4){b0, c0, b1, c1};   // ow = 2j+1
  };
  auto stageB = [&](int buf, int kt) {
    size_t gbase = (size_t)(nt * 64 + kt) * 2048 * 8;      // ushort units
    int wbase = tid & ~63;
#pragma unroll
    for (int q = 0; q < 4; ++q) {
      __builtin_amdgcn_global_load_lds(
          (const uint32_t*)(bmat2 + gbase + (size_t)(q * 512 + tid) * 8),
          (uint32_t*)&bsL[buf][(size_t)(q * 512 + wbase) * 8], 16, 0, 0);
    }
  };

  // ---- prologue: stage kt=0 into buf 0 ----
  {
    f32x4 t0v0, t0v1, t1v0, t1v1;
    float t0pw0, t0nx0, t0pw1, t0nx1, t1pw0, t1nx0, t1pw1, t1nx1;
    ldrow(pA, vA0, jA, t0v0, t0pw0, t0nx0);
    ldrow(pA + 64, vA1, jA, t0v1, t0pw1, t0nx1);
    if (hasB) {
      ldrow(pB, vB0, jB, t1v0, t1pw0, t1nx0);
      ldrow(pB + 64, vB1, jB, t1v1, t1pw1, t1nx1);
    }
    stageB(0, 0);
    wtask(0, riA, jA, t0v0, t0v1, t0pw0, t0nx0, t0pw1, t0nx1);
    if (hasB) wtask(0, riB, jB, t1v0, t1v1, t1pw0, t1nx0, t1pw1, t1nx1);
  }
  __syncthreads();

  union UF { u32x4 u; short8 s; };

  for (int kt = 0; kt < 64; ++kt) {
    int cur = kt & 1, nxt = cur ^ 1;

    // ---- issue next-tile staging early (T14) ----
    f32x4 t0v0, t0v1, t1v0, t1v1;
    float t0pw0, t0nx0, t0pw1, t0nx1, t1pw0, t1nx0, t1pw1, t1nx1;
    if (kt < 63) {
      const float* p0 = pA + (size_t)(kt + 1) * 16384;
      ldrow(p0, vA0, jA, t0v0, t0pw0, t0nx0);
      ldrow(p0 + 64, vA1, jA, t0v1, t0pw1, t0nx1);
      if (hasB) {
        const float* p1 = pB + (size_t)(kt + 1) * 16384;
        ldrow(p1, vB0, jB, t1v0, t1pw0, t1nx0);
        ldrow(p1 + 64, vB1, jB, t1v1, t1pw1, t1nx1);
      }
      stageB(nxt, kt + 1);
    }

    // ---- compute on cur ----
    const u32x4* xp4 = (const u32x4*)&xsL[cur][0];
    const u32x4* bp4 = (const u32x4*)&bsL[cur][0];
#pragma unroll
    for (int kk = 0; kk < 2; ++kk) {
      UF bf[4];
#pragma unroll
      for (int ni = 0; ni < 4; ++ni) {
        int nloc = wn * 64 + ni * 16 + lr;
        bf[ni].u = bp4[nloc * 8 + ((4 * kk + g) ^ (nloc & 7))];
      }
      __builtin_amdgcn_s_setprio(1);
#pragma unroll
      for (int mi = 0; mi < 8; ++mi) {
        int rowidx = (2 * kk + (g >> 1)) * 9 + wm * 4 + (mi >> 1) + (g & 1);
        int ow = ((mi & 1) << 4) + lr;
        UF af; af.u = xp4[rowidx * 32 + (ow >> 1) + ((ow & 1) << 4)];
#pragma unroll
        for (int ni = 0; ni < 4; ++ni)
          acc[mi][ni] = __builtin_amdgcn_mfma_f32_16x16x32_bf16(af.s, bf[ni].s, acc[mi][ni], 0, 0, 0);
      }
      __builtin_amdgcn_s_setprio(0);
    }

    // ---- write next A tile (waits its global loads via compiler vmcnt) ----
    if (kt < 63) {
      wtask(nxt, riA, jA, t0v0, t0v1, t0pw0, t0nx0, t0pw1, t0nx1);
      if (hasB) wtask(nxt, riB, jB, t1v0, t1v1, t1pw0, t1nx0, t1pw1, t1nx1);
    }
    __syncthreads();
  }

  // ---- epilogue: mask, store, per-channel sums ----
  float msk[4];
#pragma unroll
  for (int ni = 0; ni < 4; ++ni)
    msk[ni] = mask[b * 512 + nt * 256 + wn * 64 + ni * 16 + lr];

  float psum[4] = {0.f, 0.f, 0.f, 0.f}, psq[4] = {0.f, 0.f, 0.f, 0.f};
#pragma unroll
  for (int ni = 0; ni < 4; ++ni) {
    int n = nt * 256 + wn * 64 + ni * 16 + lr;
    float* op = out + (size_t)b * 524288 + (size_t)n * 1024 + OH0 * 32 + wm * 128 + g * 4;
#pragma unroll
    for (int mi = 0; mi < 8; ++mi) {
      f32x4 a = acc[mi][ni] * msk[ni];
      psum[ni] += a.x + a.y + a.z + a.w;
      psq[ni] += a.x * a.x + a.y * a.y + a.z * a.z + a.w * a.w;
      *(f32x4*)(op + mi * 16) = a;
    }
  }
#pragma unroll
  for (int ni = 0; ni < 4; ++ni) {
    float s = psum[ni], q = psq[ni];
    s += __shfl_xor(s, 16); s += __shfl_xor(s, 32);
    q += __shfl_xor(q, 16); q += __shfl_xor(q, 32);
    if (g == 0) {
      int n = nt * 256 + wn * 64 + ni * 16 + lr;
      atomicAdd(&gsum[n], s);
      atomicAdd(&gsq[n], q);
    }
  }
}

// ---------------- stage 6: BN params ----------------
__global__ void k_bnprep(const float* __restrict__ gsum, const float* __restrict__ gsq,
                         const float* __restrict__ gamma, const float* __restrict__ beta,
                         float* __restrict__ scale, float* __restrict__ shift) {
  int n = threadIdx.x;
  float mu = gsum[n] * (1.f / 32768.f);
  float var = gsq[n] * (1.f / 32768.f) - mu * mu;
  float a = gamma[n] * rsqrtf(var + 1e-5f);
  scale[n] = a;
  shift[n] = beta[n] - mu * a;
}

// ---------------- stage 7: BN apply + LeakyReLU (in place) ----------------
__global__ void k_bn(float* __restrict__ y, const float* __restrict__ scale,
                     const float* __restrict__ shift) {
  int t = blockIdx.x * 256 + threadIdx.x;
  f32x4* yp = (f32x4*)y;
#pragma unroll
  for (int i = 0; i < 8; ++i) {
    int idx = t + i * 524288;
    int n = (idx >> 8) & 511;
    f32x4 v = yp[idx];
    float a = scale[n], sh = shift[n];
    v = v * a + sh;
    v.x = v.x > 0.f ? v.x : 0.2f * v.x;
    v.y = v.y > 0.f ? v.y : 0.2f * v.y;
    v.z = v.z > 0.f ? v.z : 0.2f * v.z;
    v.w = v.w > 0.f ? v.w : 0.2f * v.w;
    yp[idx] = v;
  }
}

extern "C" void kernel_launch(void* const* d_in, const int* in_sizes, int n_in,
                              void* d_out, int out_size, void* d_ws, size_t ws_size,
                              hipStream_t stream) {
  const float* x     = (const float*)d_in[0];
  const float* w     = (const float*)d_in[1];
  const float* pos   = (const float*)d_in[2];
  const float* neg   = (const float*)d_in[3];
  const float* salw  = (const float*)d_in[4];
  const float* salb  = (const float*)d_in[5];
  const float* gamma = (const float*)d_in[6];
  const float* beta  = (const float*)d_in[7];
  float* out = (float*)d_out;
  char* ws = (char*)d_ws;

  unsigned int* absmax = (unsigned int*)(ws + WS_ABSMAX);
  float* gsum  = (float*)(ws + WS_GSUM);
  float* gsq   = (float*)(ws + WS_GSQ);
  float* scale = (float*)(ws + WS_SCALE);
  float* shift = (float*)(ws + WS_SHIFT);
  float* sub   = (float*)(ws + WS_SUB);
  float* mask  = (float*)(ws + WS_MASK);
  unsigned short* bmat2 = (unsigned short*)(ws + WS_BMAT);

  hipMemsetAsync(ws, 0, 5120, stream);   // absmax + gsum + gsq

  k_sub<<<8192, 256, 0, stream>>>(x, sub);
  k_wmax<<<256, 256, 0, stream>>>(w, absmax);
  k_mask<<<32, 512, 0, stream>>>(sub, salw, salb, mask);
  k_quant<<<1024, 256, 0, stream>>>(w, absmax, pos, neg, bmat2);
  k_gemm<<<256, 512, 0, stream>>>(x, bmat2, mask, out, gsum, gsq);
  k_bnprep<<<1, 512, 0, stream>>>(gsum, gsq, gamma, beta, scale, shift);
  k_bn<<<2048, 256, 0, stream>>>(out, scale, shift);
}

// Round 3
// 419.436 us; speedup vs baseline: 1.1037x; 1.1030x over previous
//
#include <hip/hip_runtime.h>
#include <stdint.h>

typedef __attribute__((ext_vector_type(8))) short short8;
typedef __attribute__((ext_vector_type(4))) float f32x4;
typedef __attribute__((ext_vector_type(4))) uint32_t u32x4;
typedef __attribute__((ext_vector_type(4))) unsigned short u16x4;

#define K_TOP 410

// ws layout (byte offsets)
#define WS_ABSMAX 0
#define WS_GSUM   1024
#define WS_GSQ    3072
#define WS_SCALE  5120
#define WS_SHIFT  7168
#define WS_SUB    16384      // 8192 f32
#define WS_MASK   65536      // 16384 f32
#define WS_BMAT   131072     // 4 MB: pre-tiled swizzled bf16 weights
// bmat2 layout: [nt 0..1][kt 0..63][chunk c 0..2047] x 16B, c=(n<<3)|sp,
// content = W[nt*256+n][k64 = 8*s .. 8*s+7] with s = sp ^ (n&7), k64 = cin_l*16+kh*4+kw

__device__ __forceinline__ unsigned short f2bf(float f) {
  uint32_t u = __float_as_uint(f);
  u += 0x7fffu + ((u >> 16) & 1u);   // RTNE
  return (unsigned short)(u >> 16);
}

__device__ __forceinline__ uint32_t pkbf(float a, float b) {
  uint32_t r;
  asm("v_cvt_pk_bf16_f32 %0, %1, %2" : "=v"(r) : "v"(a), "v"(b));
  return r;
}

// ---------------- stage 1: sub[b][cin] = mean |x| over 64x64 ----------------
__global__ void k_sub(const float* __restrict__ x, float* __restrict__ sub) {
  int bid = blockIdx.x;                       // b*256+cin
  const f32x4* xp = (const f32x4*)(x + (size_t)bid * 4096);
  int t = threadIdx.x;
  float s = 0.f;
#pragma unroll
  for (int i = 0; i < 4; ++i) {
    f32x4 v = xp[t + i * 256];
    s += fabsf(v.x) + fabsf(v.y) + fabsf(v.z) + fabsf(v.w);
  }
#pragma unroll
  for (int off = 32; off > 0; off >>= 1) s += __shfl_xor(s, off);
  __shared__ float red[4];
  if ((t & 63) == 0) red[t >> 6] = s;
  __syncthreads();
  if (t == 0) sub[bid] = (red[0] + red[1] + red[2] + red[3]) * (1.f / 4096.f);
}

// ---------------- stage 2: max|W| ----------------
__global__ void k_wmax(const float* __restrict__ w, unsigned int* __restrict__ wsmax) {
  int t = blockIdx.x * 256 + threadIdx.x;
  const f32x4* wp = (const f32x4*)w;
  float m = 0.f;
#pragma unroll
  for (int i = 0; i < 8; ++i) {
    f32x4 v = wp[t + i * 65536];
    m = fmaxf(m, fmaxf(fmaxf(fabsf(v.x), fabsf(v.y)), fmaxf(fabsf(v.z), fabsf(v.w))));
  }
#pragma unroll
  for (int off = 32; off > 0; off >>= 1) m = fmaxf(m, __shfl_xor(m, off));
  __shared__ float red[4];
  if ((threadIdx.x & 63) == 0) red[threadIdx.x >> 6] = m;
  __syncthreads();
  if (threadIdx.x == 0) {
    m = fmaxf(fmaxf(red[0], red[1]), fmaxf(red[2], red[3]));
    atomicMax(wsmax, __float_as_uint(m));
  }
}

// ---------------- stage 3: saliency + top-k threshold -> mask[b][cout] ----------------
__global__ void k_mask(const float* __restrict__ sub, const float* __restrict__ salw,
                       const float* __restrict__ salb, float* __restrict__ mask) {
  int b = blockIdx.x, n = threadIdx.x;  // 512 threads
  __shared__ float subs[256];
  __shared__ float sals[512];
  __shared__ float thr_s;
  if (n < 256) subs[n] = sub[b * 256 + n];
  __syncthreads();
  float acc = salb[n];
#pragma unroll 4
  for (int c = 0; c < 256; ++c) acc += subs[c] * salw[n * 256 + c];
  float sal = fabsf(acc);
  sals[n] = sal;
  __syncthreads();
  int gt = 0, eq = 0;
  for (int j = 0; j < 512; ++j) {
    float v = sals[j];
    gt += (v > sal);
    eq += (v == sal);
  }
  if (gt < K_TOP && gt + eq >= K_TOP) thr_s = sal;
  __syncthreads();
  mask[b * 512 + n] = (sal > thr_s) ? sal : 0.f;
}

// ---------------- stage 4: ternarize weight -> pre-tiled swizzled bf16 bmat2 ----------------
__global__ void k_quant(const float* __restrict__ w, const unsigned int* __restrict__ wsmax,
                        const float* __restrict__ posp, const float* __restrict__ negp,
                        unsigned short* __restrict__ bmat2) {
  int id = blockIdx.x * 256 + threadIdx.x;        // chunk id 0..262143
  int c = id & 2047;
  int ktq = (id >> 11) & 63;
  int ntq = id >> 17;
  int n = c >> 3, sp = c & 7;
  int s = sp ^ (n & 7);
  int cout = ntq * 256 + n;
  const float* src = w + (size_t)cout * 4096 + ktq * 64 + s * 8;
  float thr = 0.05f * __uint_as_float(*wsmax);
  unsigned short bp = f2bf(*posp), bn = f2bf(*negp);
  f32x4 a = *(const f32x4*)src;
  f32x4 bq = *(const f32x4*)(src + 4);
  u16x4 q0, q1;
  q0.x = a.x > thr ? bp : (a.x < -thr ? bn : (unsigned short)0);
  q0.y = a.y > thr ? bp : (a.y < -thr ? bn : (unsigned short)0);
  q0.z = a.z > thr ? bp : (a.z < -thr ? bn : (unsigned short)0);
  q0.w = a.w > thr ? bp : (a.w < -thr ? bn : (unsigned short)0);
  q1.x = bq.x > thr ? bp : (bq.x < -thr ? bn : (unsigned short)0);
  q1.y = bq.y > thr ? bp : (bq.y < -thr ? bn : (unsigned short)0);
  q1.z = bq.z > thr ? bp : (bq.z < -thr ? bn : (unsigned short)0);
  q1.w = bq.w > thr ? bp : (bq.w < -thr ? bn : (unsigned short)0);
  ((u16x4*)bmat2)[id * 2]     = q0;
  ((u16x4*)bmat2)[id * 2 + 1] = q1;
}

// ---------------- stage 5: implicit-GEMM conv, 256x256 tile, BK=64 ----------------
// M=32768, N=512, K=4096. 256 blocks (nt = wg>>7 so x-sharing pairs land on one XCD).
// 8 waves (2m x 4n), wave tile 128x64. Frags read ONCE per K-tile (24 b128/wave).
// Schedule: issue t+1 loads early -> 2 MFMA phases on cur -> pack/ds_write ->
// counted drain (loads had ~620cy to land) -> raw s_barrier.
__launch_bounds__(512, 2)
__global__ void k_gemm(const float* __restrict__ x, const unsigned short* __restrict__ bmat2,
                       const float* __restrict__ mask, float* __restrict__ out,
                       float* __restrict__ gsum, float* __restrict__ gsq) {
  __shared__ __align__(16) unsigned short xsL[2][36 * 32 * 8];   // 2 x 18 KB
  __shared__ __align__(16) unsigned short bsL[2][2048 * 8];      // 2 x 32 KB

  int tid = threadIdx.x;
  int lane = tid & 63, wid = tid >> 6;
  int wm = wid >> 2, wn = wid & 3;
  int g = lane >> 4, lr = lane & 15;

  int wg = blockIdx.x;
  int nt = wg >> 7, mt = wg & 127;       // pair (mt, mt+128) shares x, same XCD (i%8)
  int b = mt >> 2, OH0 = (mt & 3) * 8;
  const size_t xb = (size_t)b * 256 * 4096;

  // A staging task 0 (all threads): rowidx = tid>>4 (0..31), j = tid&15
  int jA = tid & 15, riA = tid >> 4;
  int c2A = riA / 9, rpA = riA - c2A * 9;
  int ihA = 2 * (OH0 + rpA) - 1;
  bool vA0 = (unsigned)ihA < 64u, vA1 = (unsigned)(ihA + 1) < 64u;
  const float* pA = x + xb + (size_t)c2A * 4096 + (long)ihA * 64 + 4 * jA;
  // task 1 (waves 0..3, lanes 0..15): rowidx = 32+wid
  bool hasB = (wid < 4) && (lane < 16);
  int riB = 32 + wid, jB = lane & 15;
  int rpB = riB - 27;
  int ihB = 2 * (OH0 + rpB) - 1;
  bool vB0 = (unsigned)ihB < 64u, vB1 = (unsigned)(ihB + 1) < 64u;
  const float* pB = x + xb + (size_t)3 * 4096 + (long)ihB * 64 + 4 * jB;

  f32x4 acc[8][4];
#pragma unroll
  for (int i = 0; i < 8; ++i)
#pragma unroll
    for (int j = 0; j < 4; ++j) acc[i][j] = (f32x4){0.f, 0.f, 0.f, 0.f};

  auto z4 = []() { return (f32x4){0.f, 0.f, 0.f, 0.f}; };

  // pack one row-pair into two im2col units; neighbors via shfl (full data in v0/v1)
  auto wtask = [&](int buf, int rowidx, int j, f32x4 v0, f32x4 v1) {
    float pw0 = __shfl_up(v0.w, 1);  if (j == 0)  pw0 = 0.f;
    float nx0 = __shfl_down(v0.x, 1); if (j == 15) nx0 = 0.f;
    float pw1 = __shfl_up(v1.w, 1);  if (j == 0)  pw1 = 0.f;
    float nx1 = __shfl_down(v1.x, 1); if (j == 15) nx1 = 0.f;
    uint32_t a0 = pkbf(pw0, v0.x), b0 = pkbf(v0.y, v0.z), c0 = pkbf(v0.w, nx0);
    uint32_t a1 = pkbf(pw1, v1.x), b1 = pkbf(v1.y, v1.z), c1 = pkbf(v1.w, nx1);
    u32x4* dst = (u32x4*)&xsL[buf][0];
    dst[rowidx * 32 + j]      = (u32x4){a0, b0, a1, b1};   // ow = 2j
    dst[rowidx * 32 + 16 + j] = (u32x4){b0, c0, b1, c1};   // ow = 2j+1
  };
  auto stageB = [&](int buf, int kt) {
    size_t gbase = (size_t)(nt * 64 + kt) * 2048 * 8;      // ushort units
    int wbase = tid & ~63;
#pragma unroll
    for (int q = 0; q < 4; ++q) {
      __builtin_amdgcn_global_load_lds(
          (const uint32_t*)(bmat2 + gbase + (size_t)(q * 512 + tid) * 8),
          (uint32_t*)&bsL[buf][(size_t)(q * 512 + wbase) * 8], 16, 0, 0);
    }
  };

  union UF { u32x4 u; short8 s; };

  // ---- prologue: stage kt=0 into buf 0 ----
  {
    f32x4 a0 = vA0 ? *(const f32x4*)pA : z4();
    f32x4 a1 = vA1 ? *(const f32x4*)(pA + 64) : z4();
    f32x4 c0 = z4(), c1 = z4();
    if (hasB) {
      c0 = vB0 ? *(const f32x4*)pB : z4();
      c1 = vB1 ? *(const f32x4*)(pB + 64) : z4();
    }
    stageB(0, 0);
    wtask(0, riA, jA, a0, a1);
    if (hasB) wtask(0, riB, jB, c0, c1);
    asm volatile("s_waitcnt vmcnt(0) lgkmcnt(0)" ::: "memory");
    __builtin_amdgcn_s_barrier();
    __builtin_amdgcn_sched_barrier(0);
  }

  for (int kt = 0; kt < 64; ++kt) {
    int cur = kt & 1, nxt = cur ^ 1;
    bool pre = (kt < 63);

    // ---- issue t+1 loads first (A regs, then B global_load_lds) ----
    f32x4 a0, a1, c0, c1;
    if (pre) {
      const float* p0 = pA + (size_t)(kt + 1) * 16384;
      a0 = vA0 ? *(const f32x4*)p0 : z4();
      a1 = vA1 ? *(const f32x4*)(p0 + 64) : z4();
      if (hasB) {
        const float* p1 = pB + (size_t)(kt + 1) * 16384;
        c0 = vB0 ? *(const f32x4*)p1 : z4();
        c1 = vB1 ? *(const f32x4*)(p1 + 64) : z4();
      }
      stageB(nxt, kt + 1);
    }

    // ---- 2 phases of 32 MFMA on cur; each frag read exactly once ----
    const u32x4* xp4 = (const u32x4*)&xsL[cur][0];
    const u32x4* bp4 = (const u32x4*)&bsL[cur][0];
#pragma unroll
    for (int kk = 0; kk < 2; ++kk) {
      UF bf[4];
#pragma unroll
      for (int ni = 0; ni < 4; ++ni) {
        int nloc = wn * 64 + ni * 16 + lr;
        bf[ni].u = bp4[nloc * 8 + ((4 * kk + g) ^ (nloc & 7))];
      }
      UF af[8];
#pragma unroll
      for (int mi = 0; mi < 8; ++mi) {
        int rowidx = (2 * kk + (g >> 1)) * 9 + wm * 4 + (mi >> 1) + (g & 1);
        int ow = ((mi & 1) << 4) + lr;
        af[mi].u = xp4[rowidx * 32 + (ow >> 1) + ((ow & 1) << 4)];
      }
      __builtin_amdgcn_s_setprio(1);
#pragma unroll
      for (int mi = 0; mi < 8; ++mi)
#pragma unroll
        for (int ni = 0; ni < 4; ++ni)
          acc[mi][ni] = __builtin_amdgcn_mfma_f32_16x16x32_bf16(af[mi].s, bf[ni].s, acc[mi][ni], 0, 0, 0);
      __builtin_amdgcn_s_setprio(0);
      if (kk == 0) __builtin_amdgcn_s_barrier();   // phase-align (no drain needed)
    }

    // ---- pack + write next A tile (compiler auto-waits A regs at vmcnt(4)) ----
    if (pre) {
      wtask(nxt, riA, jA, a0, a1);
      if (hasB) wtask(nxt, riB, jB, c0, c1);
    }
    // counted drain: B-gloads were issued ~2 MFMA phases (~620cy) ago
    asm volatile("s_waitcnt vmcnt(0) lgkmcnt(0)" ::: "memory");
    __builtin_amdgcn_s_barrier();
    __builtin_amdgcn_sched_barrier(0);
  }

  // ---- epilogue: mask, store, per-channel sums ----
  float msk[4];
#pragma unroll
  for (int ni = 0; ni < 4; ++ni)
    msk[ni] = mask[b * 512 + nt * 256 + wn * 64 + ni * 16 + lr];

  float psum[4] = {0.f, 0.f, 0.f, 0.f}, psq[4] = {0.f, 0.f, 0.f, 0.f};
#pragma unroll
  for (int ni = 0; ni < 4; ++ni) {
    int n = nt * 256 + wn * 64 + ni * 16 + lr;
    float* op = out + (size_t)b * 524288 + (size_t)n * 1024 + OH0 * 32 + wm * 128 + g * 4;
#pragma unroll
    for (int mi = 0; mi < 8; ++mi) {
      f32x4 a = acc[mi][ni] * msk[ni];
      psum[ni] += a.x + a.y + a.z + a.w;
      psq[ni] += a.x * a.x + a.y * a.y + a.z * a.z + a.w * a.w;
      *(f32x4*)(op + mi * 16) = a;
    }
  }
#pragma unroll
  for (int ni = 0; ni < 4; ++ni) {
    float s = psum[ni], q = psq[ni];
    s += __shfl_xor(s, 16); s += __shfl_xor(s, 32);
    q += __shfl_xor(q, 16); q += __shfl_xor(q, 32);
    if (g == 0) {
      int n = nt * 256 + wn * 64 + ni * 16 + lr;
      atomicAdd(&gsum[n], s);
      atomicAdd(&gsq[n], q);
    }
  }
}

// ---------------- stage 6: BN params ----------------
__global__ void k_bnprep(const float* __restrict__ gsum, const float* __restrict__ gsq,
                         const float* __restrict__ gamma, const float* __restrict__ beta,
                         float* __restrict__ scale, float* __restrict__ shift) {
  int n = threadIdx.x;
  float mu = gsum[n] * (1.f / 32768.f);
  float var = gsq[n] * (1.f / 32768.f) - mu * mu;
  float a = gamma[n] * rsqrtf(var + 1e-5f);
  scale[n] = a;
  shift[n] = beta[n] - mu * a;
}

// ---------------- stage 7: BN apply + LeakyReLU (in place) ----------------
__global__ void k_bn(float* __restrict__ y, const float* __restrict__ scale,
                     const float* __restrict__ shift) {
  int t = blockIdx.x * 256 + threadIdx.x;
  f32x4* yp = (f32x4*)y;
#pragma unroll
  for (int i = 0; i < 8; ++i) {
    int idx = t + i * 524288;
    int n = (idx >> 8) & 511;
    f32x4 v = yp[idx];
    float a = scale[n], sh = shift[n];
    v = v * a + sh;
    v.x = v.x > 0.f ? v.x : 0.2f * v.x;
    v.y = v.y > 0.f ? v.y : 0.2f * v.y;
    v.z = v.z > 0.f ? v.z : 0.2f * v.z;
    v.w = v.w > 0.f ? v.w : 0.2f * v.w;
    yp[idx] = v;
  }
}

extern "C" void kernel_launch(void* const* d_in, const int* in_sizes, int n_in,
                              void* d_out, int out_size, void* d_ws, size_t ws_size,
                              hipStream_t stream) {
  const float* x     = (const float*)d_in[0];
  const float* w     = (const float*)d_in[1];
  const float* pos   = (const float*)d_in[2];
  const float* neg   = (const float*)d_in[3];
  const float* salw  = (const float*)d_in[4];
  const float* salb  = (const float*)d_in[5];
  const float* gamma = (const float*)d_in[6];
  const float* beta  = (const float*)d_in[7];
  float* out = (float*)d_out;
  char* ws = (char*)d_ws;

  unsigned int* absmax = (unsigned int*)(ws + WS_ABSMAX);
  float* gsum  = (float*)(ws + WS_GSUM);
  float* gsq   = (float*)(ws + WS_GSQ);
  float* scale = (float*)(ws + WS_SCALE);
  float* shift = (float*)(ws + WS_SHIFT);
  float* sub   = (float*)(ws + WS_SUB);
  float* mask  = (float*)(ws + WS_MASK);
  unsigned short* bmat2 = (unsigned short*)(ws + WS_BMAT);

  hipMemsetAsync(ws, 0, 5120, stream);   // absmax + gsum + gsq

  k_sub<<<8192, 256, 0, stream>>>(x, sub);
  k_wmax<<<256, 256, 0, stream>>>(w, absmax);
  k_mask<<<32, 512, 0, stream>>>(sub, salw, salb, mask);
  k_quant<<<1024, 256, 0, stream>>>(w, absmax, pos, neg, bmat2);
  k_gemm<<<256, 512, 0, stream>>>(x, bmat2, mask, out, gsum, gsq);
  k_bnprep<<<1, 512, 0, stream>>>(gsum, gsq, gamma, beta, scale, shift);
  k_bn<<<2048, 256, 0, stream>>>(out, scale, shift);
}